// Round 5
// baseline (420.848 us; speedup 1.0000x reference)
//
#include <hip/hip_runtime.h>
#include <math.h>

#define DELTA_ 1e-6f
#define IFACE_ 471
#define XI_STRIDE 480

// workspace offsets (in floats)
#define OFF_XI    0            // 32*480
#define OFF_RKN   15360        // 32*4*64
#define OFF_RS    23552        // 32*4
#define OFF_ER    23680        // 32*64
#define OFF_WV    25728        // 32*64
#define OFF_RM    27776        // 32*12
#define OFF_WW    28160        // 32*1024
#define OFF_WWRW  60928        // 32*4*1024
#define OFF_PRD   192000       // 32*4
#define OFF_WRD   192128       // 32*4
#define OFF_INVN  192256       // 32*1024
#define OFF_DIAG  225024       // 32*1024
#define OFF_NM    257792       // 32*1024*64
#define OFF_RAP   2354944      // 32*2cc*4r*1024
#define OFF_RBP   2617088      // 32*2cc*4r*1024
#define OFF_SAP   2879232      // 32*16rc*4r*1024
#define OFF_SBP   4976384      // 32*16rc*4r*1024
// total 7073536 floats = 27 MB

__device__ __forceinline__ float sigm_(float x){ return 1.f/(1.f+expf(-x)); }
__device__ __forceinline__ float softp_(float x){ return fmaxf(x,0.f)+log1pf(expf(-fabsf(x))); }
__device__ __forceinline__ float dot4_(float4 a, float4 b){ return a.x*b.x+a.y*b.y+a.z*b.z+a.w*b.w; }

// ---------------- K1: xi = x @ W_if + b_if ----------------
__global__ __launch_bounds__(256) void k_xi(const float* __restrict__ x,
    const float* __restrict__ W, const float* __restrict__ bias,
    float* __restrict__ xi) {
  int b = blockIdx.x;
  int j0 = blockIdx.y*64;
  int t = threadIdx.x;
  int jl = t & 63, kq = t >> 6;
  __shared__ __align__(16) float sx[1024];
  __shared__ float s_part[256];
  for (int q=t; q<256; q+=256) ((float4*)sx)[q] = ((const float4*)(x + b*1024))[q];
  __syncthreads();
  int j = j0 + jl;
  int jc = j < IFACE_ ? j : IFACE_-1;
  float acc = 0.f;
  const float* Wp = W + (size_t)kq*256*IFACE_ + jc;
  #pragma unroll 4
  for (int k=0;k<256;++k) acc += sx[kq*256+k]*Wp[(size_t)k*IFACE_];
  s_part[t] = acc;
  __syncthreads();
  if (t < 64 && (j0+t) < IFACE_) {
    xi[b*XI_STRIDE + j0+t] = s_part[t]+s_part[64+t]+s_part[128+t]+s_part[192+t] + bias[j0+t];
  }
}

// ---------------- K2: per-batch: activations, wcw, usage, sort/alloc, ww ----------------
__global__ __launch_bounds__(256) void k_batch(
    const float* __restrict__ xi, const float* __restrict__ memory,
    const float* __restrict__ usage, const float* __restrict__ read_w,
    const float* __restrict__ write_w, const float* __restrict__ precedence,
    float* __restrict__ rkn, float* __restrict__ rs, float* __restrict__ er,
    float* __restrict__ wv, float* __restrict__ rm, float* __restrict__ ww_out,
    float* __restrict__ wwrw, float* __restrict__ prd, float* __restrict__ wrd) {
  int b = blockIdx.x; int t = threadIdx.x;
  int lane = t & 63; int wave = t >> 6;
  __shared__ float s_act[472];
  __shared__ __align__(16) float s_key[64];
  __shared__ float s_wcw[1024];
  __shared__ unsigned long long s_k64[1024];
  __shared__ float s_ps[1024];
  __shared__ float s_alloc[1024];
  __shared__ float s_red[32];
  __shared__ float s_bc[2];

  for (int q = t; q < IFACE_; q += 256) {
    float v = xi[b*XI_STRIDE+q];
    float a;
    if      (q < 256) a = tanhf(v);
    else if (q < 260) a = softp_(v);
    else if (q < 324) a = tanhf(v);
    else if (q < 325) a = softp_(v);
    else if (q < 389) a = sigm_(v);
    else if (q < 453) a = tanhf(v);
    else if (q < 459) a = sigm_(v);
    else              a = v;
    s_act[q] = a;
  }
  __syncthreads();
  if (t < 4) {
    float m0=s_act[459+3*t], m1=s_act[460+3*t], m2=s_act[461+3*t];
    float mx=fmaxf(m0,fmaxf(m1,m2));
    float e0=expf(m0-mx), e1=expf(m1-mx), e2=expf(m2-mx);
    float s=e0+e1+e2;
    rm[b*12+3*t+0]=e0/s; rm[b*12+3*t+1]=e1/s; rm[b*12+3*t+2]=e2/s;
  }
  if (t < 64) { er[b*64+t]=s_act[325+t]; wv[b*64+t]=s_act[389+t]; }
  {
    int r = wave;
    float v = s_act[r*64+lane];
    float ss = v*v;
    for (int off=32; off; off>>=1) ss += __shfl_xor(ss, off);
    rkn[((size_t)b*4+r)*64+lane] = v / (sqrtf(ss)+DELTA_);
    if (lane==0) rs[b*4+r] = s_act[256+r];
  }
  if (wave==0) {
    float v = s_act[260+lane];
    float ss=v*v;
    for (int off=32; off; off>>=1) ss += __shfl_xor(ss, off);
    s_key[lane] = v/(sqrtf(ss)+DELTA_);
  }
  __syncthreads();
  float wstr = s_act[324], agv = s_act[457], wgv = s_act[458];

  for (int n=t; n<1024; n+=256) {
    const float4* row = (const float4*)(memory + ((size_t)b*1024+n)*64);
    float dot=0.f, nn2=0.f;
    #pragma unroll
    for (int w4=0; w4<16; ++w4) {
      float4 m4 = row[w4];
      float4 k4 = ((const float4*)s_key)[w4];
      dot += dot4_(m4,k4);
      nn2 += dot4_(m4,m4);
    }
    s_wcw[n] = dot/(sqrtf(nn2)+DELTA_) * wstr;
  }
  __syncthreads();
  {
    float lm=-1e30f;
    for (int n=t;n<1024;n+=256) lm=fmaxf(lm,s_wcw[n]);
    for (int off=32;off;off>>=1) lm=fmaxf(lm,__shfl_xor(lm,off));
    if (lane==0) s_red[wave]=lm;
    __syncthreads();
    if (t==0) s_bc[0]=fmaxf(fmaxf(s_red[0],s_red[1]),fmaxf(s_red[2],s_red[3]));
    __syncthreads();
    float mx=s_bc[0], ls=0.f;
    for (int n=t;n<1024;n+=256){ float e=expf(s_wcw[n]-mx); s_wcw[n]=e; ls+=e; }
    for (int off=32;off;off>>=1) ls+=__shfl_xor(ls,off);
    if (lane==0) s_red[wave]=ls;
    __syncthreads();
    if (t==0) s_bc[1]=s_red[0]+s_red[1]+s_red[2]+s_red[3];
    __syncthreads();
    float inv=1.f/s_bc[1];
    for (int n=t;n<1024;n+=256) s_wcw[n]*=inv;
  }
  __syncthreads();

  for (int n=t; n<1024; n+=256) {
    float us = usage[b*1024+n];
    float wwi = write_w[b*1024+n];
    float u = us + (1.f-us)*wwi;
    float psi = 1.f;
    #pragma unroll
    for (int r=0;r<4;++r) psi *= (1.f - s_act[453+r]*read_w[((size_t)b*4+r)*1024+n]);
    u *= psi;
    u = DELTA_ + (1.f-DELTA_)*u;
    unsigned int ub = __float_as_uint(u);
    s_k64[n] = ((unsigned long long)ub<<32) | (unsigned int)n;
  }

  for (int k=2; k<=1024; k<<=1) {
    for (int j=k>>1; j>0; j>>=1) {
      __syncthreads();
      for (int idx=t; idx<1024; idx+=256) {
        int partner = idx ^ j;
        if (partner > idx) {
          unsigned long long a=s_k64[idx], c=s_k64[partner];
          bool asc = ((idx & k) == 0);
          bool sw = asc ? (a > c) : (a < c);
          if (sw) { s_k64[idx]=c; s_k64[partner]=a; }
        }
      }
    }
  }
  __syncthreads();

  for (int n=t;n<1024;n+=256) s_ps[n] = __uint_as_float((unsigned int)(s_k64[n]>>32));
  __syncthreads();
  for (int off=1; off<1024; off<<=1) {
    float tmp[4];
    #pragma unroll
    for (int m=0;m<4;++m){ int n=t+256*m; tmp[m] = (n>=off)? s_ps[n-off] : 1.f; }
    __syncthreads();
    #pragma unroll
    for (int m=0;m<4;++m){ int n=t+256*m; s_ps[n] *= tmp[m]; }
    __syncthreads();
  }
  for (int n=t;n<1024;n+=256) {
    unsigned long long kv = s_k64[n];
    float su = __uint_as_float((unsigned int)(kv>>32));
    int oi = (int)(kv & 0xffffffffu);
    float prod = (n==0)?1.f:s_ps[n-1];
    s_alloc[oi] = (1.f-su)*prod;
  }
  __syncthreads();

  float pp[4]={0,0,0,0}, wp[4]={0,0,0,0};
  for (int n=t;n<1024;n+=256) {
    float w_ = wgv*(agv*s_alloc[n] + (1.f-agv)*s_wcw[n]);
    ww_out[b*1024+n]=w_;
    float pn = precedence[b*1024+n];
    #pragma unroll
    for (int r=0;r<4;++r){
      float rwv = read_w[((size_t)b*4+r)*1024+n];
      wwrw[((size_t)b*4+r)*1024+n] = w_*rwv;
      pp[r] += pn*rwv;
      wp[r] += w_*rwv;
    }
  }
  #pragma unroll
  for (int r=0;r<4;++r){
    for (int off=32;off;off>>=1){ pp[r]+=__shfl_xor(pp[r],off); wp[r]+=__shfl_xor(wp[r],off); }
  }
  if (lane==0){
    #pragma unroll
    for (int r=0;r<4;++r){ s_red[wave*8+r]=pp[r]; s_red[wave*8+4+r]=wp[r]; }
  }
  __syncthreads();
  if (t<4)              prd[b*4+t]   = s_red[t]+s_red[8+t]+s_red[16+t]+s_red[24+t];
  else if (t<8){ int r=t-4; wrd[b*4+r] = s_red[4+r]+s_red[12+r]+s_red[20+r]+s_red[28+r]; }
}

// ---------------- K3: new memory + row inverse norms ----------------
__global__ __launch_bounds__(256) void k_newmem(const float* __restrict__ memory,
    const float* __restrict__ ww, const float* __restrict__ er,
    const float* __restrict__ wv, float* __restrict__ newmem, float* __restrict__ invn) {
  int b = blockIdx.x;
  int n0 = blockIdx.y*64;
  int t = threadIdx.x;
  int lane16 = t & 15, rl = t >> 4;
  __shared__ float s_ww[64];
  __shared__ __align__(16) float s_er[64];
  __shared__ __align__(16) float s_wv[64];
  if (t < 64) s_ww[t] = ww[b*1024 + n0 + t];
  else if (t < 128) s_er[t-64] = er[b*64 + (t-64)];
  else if (t < 192) s_wv[t-128] = wv[b*64 + (t-128)];
  __syncthreads();
  float4 e4 = ((const float4*)s_er)[lane16];
  float4 v4 = ((const float4*)s_wv)[lane16];
  #pragma unroll
  for (int p=0;p<4;++p) {
    int rloc = p*16 + rl;
    int row = n0 + rloc;
    float wn = s_ww[rloc];
    size_t i4 = ((size_t)b*1024+row)*16 + lane16;
    float4 m4 = ((const float4*)memory)[i4];
    float4 nv;
    nv.x = m4.x*(1.f-wn*e4.x) + wn*v4.x;
    nv.y = m4.y*(1.f-wn*e4.y) + wn*v4.y;
    nv.z = m4.z*(1.f-wn*e4.z) + wn*v4.z;
    nv.w = m4.w*(1.f-wn*e4.w) + wn*v4.w;
    ((float4*)newmem)[i4] = nv;
    float ss = dot4_(nv,nv);
    ss += __shfl_xor(ss,1); ss += __shfl_xor(ss,2);
    ss += __shfl_xor(ss,4); ss += __shfl_xor(ss,8);
    if (lane16==0) invn[b*1024+row] = 1.f/(sqrtf(ss)+DELTA_);
  }
}

// ---------------- K4: single-RM scan; shared reads feed both phases; coalesced stores ----------------
// grid (32 b, 16 rc, 2 cc). Block: 64 rows x 512 cols (8 tiles of 64x64).
// Round-2's compute core (one RM read per cell feeds BOTH the row-dot and col-sum
// phases; no CM array, no transpose) with its measured failure mode fixed:
// round-2's WRITE_SIZE blew 18.5->60 MB from partial-wave stores (RMW traffic).
// Here every global store is full-wave coalesced: after the g-butterfly reduce
// (all lanes hold the tile col-sum), lane lc picks component lc&3 of the float4
// at lane lc>>2 via 4 __shfl + select; same trick redistributes the final row
// dots. LDS = RM only (17.4 KB, half of round-4) -> ~2x blocks/CU.
// Lane map: lane = 16*g + c4 (g=0..3, c4=0..15), r = wave = reader id.
// Per tile per thread: 4 ds_write_b128 + 16 ds_read_b128 + 24 shfl. All LDS
// b128 ops use stride-17-float4 -> bank-group evenly spread, conflict-free.
__global__ __launch_bounds__(256) void k_scan(const float* __restrict__ L,
    const float* __restrict__ read_w, const float* __restrict__ wwrw,
    float* __restrict__ RAp, float* __restrict__ RBp,
    float* __restrict__ SAp, float* __restrict__ SBp,
    float* __restrict__ diag) {
  int b = blockIdx.x, rc = blockIdx.y, cc = blockIdx.z;
  int i0 = rc*64;
  int q = threadIdx.x;
  int r = q>>6, lc = q&63;
  int g = (q>>4)&3, c4 = q&15;
  __shared__ __align__(16) float RM[64*68];   // row-major tile, stride 17 float4

  const float4* L4 = (const float4*)(L + (size_t)b*1048576);
  const float* wA = read_w + ((size_t)b*4+r)*1024;
  const float* wB = wwrw   + ((size_t)b*4+r)*1024;

  // tile-invariant row weights for rows i0 + 4*it + g (32 VGPRs, loaded once, L1-hot)
  float wrA[16], wrB[16];
  #pragma unroll
  for (int it=0; it<16; ++it) {
    wrA[it] = wA[i0 + 4*it + g];
    wrB[it] = wB[i0 + 4*it + g];
  }

  float ra[16], rb[16];
  #pragma unroll
  for (int it=0; it<16; ++it) { ra[it]=0.f; rb[it]=0.f; }

  float4 pre[4];
  {
    int tc0 = cc*512;
    #pragma unroll
    for (int m=0;m<4;++m){
      int flat = q + 256*m;
      int row = flat>>4, cq = flat&15;
      pre[m] = L4[(size_t)(i0+row)*256 + (tc0>>2) + cq];
    }
  }
  for (int t=0;t<8;++t) {
    int tc0 = cc*512 + t*64;
    // per-tile col weights (per-lane c4, 4-way lane dup, L1-hot)
    float4 wcA = *(const float4*)(wA + tc0 + 4*c4);
    float4 wcB = *(const float4*)(wB + tc0 + 4*c4);
    __syncthreads();   // previous tile's LDS reads complete
    #pragma unroll
    for (int m=0;m<4;++m){
      int flat = q + 256*m;
      int row = flat>>4, cq = flat&15;
      ((float4*)RM)[row*17 + cq] = pre[m];    // bank-group (row+cq)%8: even spread
    }
    __syncthreads();   // tile visible
    if (t<7){
      int nc0 = tc0 + 64;
      #pragma unroll
      for (int m=0;m<4;++m){
        int flat = q + 256*m;
        int row = flat>>4, cq = flat&15;
        pre[m] = L4[(size_t)(i0+row)*256 + (nc0>>2) + cq];
      }
    }
    if (i0 == tc0 && q < 64) diag[b*1024 + i0 + q] = RM[q*68 + q];
    // fused dot loop: each cell read once, feeds row dots (A) and col sums (B)
    float4 sa = {0.f,0.f,0.f,0.f}, sb = {0.f,0.f,0.f,0.f};
    #pragma unroll
    for (int it=0; it<16; ++it) {
      float4 cell = ((const float4*)RM)[(4*it+g)*17 + c4];   // bank-group (4it+g+c4)%8: even
      ra[it] += dot4_(cell, wcA);
      rb[it] += dot4_(cell, wcB);
      float a_ = wrA[it], b_ = wrB[it];
      sa.x += cell.x*a_; sa.y += cell.y*a_; sa.z += cell.z*a_; sa.w += cell.w*a_;
      sb.x += cell.x*b_; sb.y += cell.y*b_; sb.z += cell.z*b_; sb.w += cell.w*b_;
    }
    // reduce col partials across g (xor 32, 16) -> all lanes hold full col sums
    #pragma unroll
    for (int off=32; off>=16; off>>=1) {
      sa.x += __shfl_xor(sa.x,off); sa.y += __shfl_xor(sa.y,off);
      sa.z += __shfl_xor(sa.z,off); sa.w += __shfl_xor(sa.w,off);
      sb.x += __shfl_xor(sb.x,off); sb.y += __shfl_xor(sb.y,off);
      sb.z += __shfl_xor(sb.z,off); sb.w += __shfl_xor(sb.w,off);
    }
    // redistribute: lane lc takes component lc&3 of float4 at lane lc>>2,
    // then one full-wave coalesced scalar store per array (no partial-wave stores)
    {
      int cs = lc>>2, sel = lc&3;
      float ax=__shfl(sa.x,cs), ay=__shfl(sa.y,cs), az=__shfl(sa.z,cs), aw=__shfl(sa.w,cs);
      float bx=__shfl(sb.x,cs), by=__shfl(sb.y,cs), bz=__shfl(sb.z,cs), bw=__shfl(sb.w,cs);
      float av = sel==0?ax: sel==1?ay: sel==2?az:aw;
      float bv = sel==0?bx: sel==1?by: sel==2?bz:bw;
      size_t base = (((size_t)(b*16+rc))*4+r)*1024 + tc0;
      SAp[base + lc] = av;
      SBp[base + lc] = bv;
    }
  }
  // final: reduce row dots across c4 (bits 0..3), all lanes of group g hold row 4it+g
  #pragma unroll
  for (int it=0; it<16; ++it) {
    #pragma unroll
    for (int off=1; off<=8; off<<=1) {
      ra[it] += __shfl_xor(ra[it],off);
      rb[it] += __shfl_xor(rb[it],off);
    }
  }
  // lane lc needs row lc = 4*(lc>>2)+(lc&3): take ra[lc>>2] from lane 16*(lc&3)
  {
    float fa=0.f, fb=0.f;
    int srcl = (lc&3)<<4;
    #pragma unroll
    for (int it=0; it<16; ++it) {
      float va = __shfl(ra[it], srcl);
      float vb = __shfl(rb[it], srcl);
      if ((lc>>2)==it) { fa=va; fb=vb; }
    }
    size_t baseA = (((size_t)(b*2+cc))*4+r)*1024 + i0;
    RAp[baseA + lc] = fa;   // full-wave coalesced
    RBp[baseA + lc] = fb;
  }
}

// ---------------- K5: content softmax + combine + readout (fused) ----------------
__global__ __launch_bounds__(256) void k_read(
    const float* __restrict__ newmem, const float* __restrict__ invn,
    const float* __restrict__ rkn, const float* __restrict__ rs,
    const float* __restrict__ rm, const float* __restrict__ RAp,
    const float* __restrict__ RBp, const float* __restrict__ SAp,
    const float* __restrict__ SBp, const float* __restrict__ ww,
    const float* __restrict__ precedence, const float* __restrict__ read_w,
    const float* __restrict__ diag, const float* __restrict__ prd,
    const float* __restrict__ wrd, float* __restrict__ out) {
  int b=blockIdx.x, r=blockIdx.y;
  int t=threadIdx.x, lane=t&63, wave=t>>6;
  int lane16 = t & 15, rl = t >> 4;
  __shared__ __align__(16) float s_key[64];
  __shared__ float s_arr[1024];
  __shared__ float s_red[4];
  __shared__ float s_bc[2];
  __shared__ __align__(16) float4 s_acc[16][16];
  if (t<64) s_key[t]=rkn[((size_t)b*4+r)*64+t];
  __syncthreads();
  float rstr = rs[b*4+r];
  float4 key4 = ((const float4*)s_key)[lane16];
  for (int p=0;p<64;++p) {
    int row = p*16 + rl;
    float4 m4 = ((const float4*)newmem)[((size_t)b*1024+row)*16 + lane16];
    float d = dot4_(m4, key4);
    d += __shfl_xor(d,1); d += __shfl_xor(d,2);
    d += __shfl_xor(d,4); d += __shfl_xor(d,8);
    if (lane16==0) s_arr[row] = d * invn[b*1024+row] * rstr;
  }
  __syncthreads();
  {
    float lm=-1e30f;
    for (int n=t;n<1024;n+=256) lm=fmaxf(lm,s_arr[n]);
    for (int off=32;off;off>>=1) lm=fmaxf(lm,__shfl_xor(lm,off));
    if (lane==0) s_red[wave]=lm;
    __syncthreads();
    if (t==0) s_bc[0]=fmaxf(fmaxf(s_red[0],s_red[1]),fmaxf(s_red[2],s_red[3]));
    __syncthreads();
    float mx=s_bc[0], ls=0.f;
    for (int n=t;n<1024;n+=256){ float e=expf(s_arr[n]-mx); s_arr[n]=e; ls+=e; }
    for (int off=32;off;off>>=1) ls+=__shfl_xor(ls,off);
    if (lane==0) s_red[wave]=ls;
    __syncthreads();
    if (t==0) s_bc[1]=s_red[0]+s_red[1]+s_red[2]+s_red[3];
    __syncthreads();
    float inv=1.f/s_bc[1];
    for (int n=t;n<1024;n+=256) s_arr[n]*=inv;
  }
  __syncthreads();
  float m0=rm[b*12+r*3+0], m1=rm[b*12+r*3+1], m2=rm[b*12+r*3+2];
  float pd=prd[b*4+r], wd=wrd[b*4+r];
  // thread-local per-n combine: no cross-thread hazard, no barriers needed
  for (int n=t;n<1024;n+=256) {
    float ra=0.f, rb=0.f;
    #pragma unroll
    for (int cc=0;cc<2;++cc){
      ra += RAp[(((size_t)(b*2+cc))*4+r)*1024+n];
      rb += RBp[(((size_t)(b*2+cc))*4+r)*1024+n];
    }
    float sa=0.f, sb=0.f;
    #pragma unroll
    for (int rc=0;rc<16;++rc){
      sa+=SAp[(((size_t)(b*16+rc))*4+r)*1024+n];
      sb+=SBp[(((size_t)(b*16+rc))*4+r)*1024+n];
    }
    float w_ = ww[b*1024+n];
    float pn = precedence[b*1024+n];
    float rwv= read_w[((size_t)b*4+r)*1024+n];
    float dg = diag[b*1024+n];
    float fwd = (1.f-w_)*ra - rb + w_*pd - ((1.f-2.f*w_)*dg + w_*pn)*rwv;
    float bwd = (1.f-w_)*sa - sb + pn*(wd - w_*rwv) - (1.f-2.f*w_)*dg*rwv;
    float crw = s_arr[n];
    s_arr[n] = m0*bwd + m1*crw + m2*fwd;
  }
  __syncthreads();
  float4 acc = {0,0,0,0};
  for (int p=0;p<64;++p) {
    int row = p*16 + rl;
    float4 m4 = ((const float4*)newmem)[((size_t)b*1024+row)*16 + lane16];
    float s = s_arr[row];
    acc.x += s*m4.x; acc.y += s*m4.y; acc.z += s*m4.z; acc.w += s*m4.w;
  }
  s_acc[rl][lane16] = acc;
  __syncthreads();
  if (t < 16) {
    float4 tot = {0,0,0,0};
    #pragma unroll
    for (int g=0; g<16; ++g) {
      float4 v = s_acc[g][t];
      tot.x+=v.x; tot.y+=v.y; tot.z+=v.z; tot.w+=v.w;
    }
    ((float4*)(out + (b*4+r)*64))[t] = tot;
  }
}

extern "C" void kernel_launch(void* const* d_in, const int* in_sizes, int n_in,
                              void* d_out, int out_size, void* d_ws, size_t ws_size,
                              hipStream_t stream) {
  const float* x      = (const float*)d_in[0];
  const float* W_if   = (const float*)d_in[1];
  const float* b_if   = (const float*)d_in[2];
  const float* memory = (const float*)d_in[3];
  const float* link   = (const float*)d_in[4];
  const float* prec   = (const float*)d_in[5];
  const float* read_w = (const float*)d_in[6];
  const float* write_w= (const float*)d_in[7];
  const float* usage  = (const float*)d_in[8];
  float* out = (float*)d_out;
  float* ws = (float*)d_ws;

  float* xi   = ws + OFF_XI;
  float* rkn  = ws + OFF_RKN;
  float* rs   = ws + OFF_RS;
  float* er   = ws + OFF_ER;
  float* wv   = ws + OFF_WV;
  float* rm   = ws + OFF_RM;
  float* wwp  = ws + OFF_WW;
  float* wwrw = ws + OFF_WWRW;
  float* prd  = ws + OFF_PRD;
  float* wrd  = ws + OFF_WRD;
  float* invn = ws + OFF_INVN;
  float* diag = ws + OFF_DIAG;
  float* nm   = ws + OFF_NM;
  float* RAp  = ws + OFF_RAP;
  float* RBp  = ws + OFF_RBP;
  float* SAp  = ws + OFF_SAP;
  float* SBp  = ws + OFF_SBP;

  k_xi<<<dim3(32,8), 256, 0, stream>>>(x, W_if, b_if, xi);
  k_batch<<<dim3(32), 256, 0, stream>>>(xi, memory, usage, read_w, write_w, prec,
                                        rkn, rs, er, wv, rm, wwp, wwrw, prd, wrd);
  k_scan<<<dim3(32,16,2), 256, 0, stream>>>(link, read_w, wwrw, RAp, RBp, SAp, SBp, diag);
  k_newmem<<<dim3(32,16), 256, 0, stream>>>(memory, wwp, er, wv, nm, invn);
  k_read<<<dim3(32,4), 256, 0, stream>>>(nm, invn, rkn, rs, rm, RAp, RBp, SAp, SBp,
                                         wwp, prec, read_w, diag, prd, wrd, out);
}

// Round 6
// 339.695 us; speedup vs baseline: 1.2389x; 1.2389x over previous
//
#include <hip/hip_runtime.h>
#include <math.h>

#define DELTA_ 1e-6f
#define IFACE_ 471
#define XI_STRIDE 480

// workspace offsets (in floats)
#define OFF_XI    0            // 32*480
#define OFF_RKN   15360        // 32*4*64
#define OFF_RS    23552        // 32*4
#define OFF_ER    23680        // 32*64
#define OFF_WV    25728        // 32*64
#define OFF_RM    27776        // 32*12
#define OFF_WW    28160        // 32*1024
#define OFF_WWRW  60928        // 32*4*1024
#define OFF_PRD   192000       // 32*4
#define OFF_WRD   192128       // 32*4
#define OFF_INVN  192256       // 32*1024
#define OFF_DIAG  225024       // 32*1024
#define OFF_NM    257792       // 32*1024*64
#define OFF_RAP   2354944      // 32*2cc*4r*1024
#define OFF_RBP   2617088      // 32*2cc*4r*1024
#define OFF_SAP   2879232      // 32*16rc*4r*1024
#define OFF_SBP   4976384      // 32*16rc*4r*1024
// total 7073536 floats = 27 MB

__device__ __forceinline__ float sigm_(float x){ return 1.f/(1.f+expf(-x)); }
__device__ __forceinline__ float softp_(float x){ return fmaxf(x,0.f)+log1pf(expf(-fabsf(x))); }
__device__ __forceinline__ float dot4_(float4 a, float4 b){ return a.x*b.x+a.y*b.y+a.z*b.z+a.w*b.w; }

// ---------------- K1: xi = x @ W_if + b_if ----------------
__global__ __launch_bounds__(256) void k_xi(const float* __restrict__ x,
    const float* __restrict__ W, const float* __restrict__ bias,
    float* __restrict__ xi) {
  int b = blockIdx.x;
  int j0 = blockIdx.y*64;
  int t = threadIdx.x;
  int jl = t & 63, kq = t >> 6;
  __shared__ __align__(16) float sx[1024];
  __shared__ float s_part[256];
  for (int q=t; q<256; q+=256) ((float4*)sx)[q] = ((const float4*)(x + b*1024))[q];
  __syncthreads();
  int j = j0 + jl;
  int jc = j < IFACE_ ? j : IFACE_-1;
  float acc = 0.f;
  const float* Wp = W + (size_t)kq*256*IFACE_ + jc;
  #pragma unroll 4
  for (int k=0;k<256;++k) acc += sx[kq*256+k]*Wp[(size_t)k*IFACE_];
  s_part[t] = acc;
  __syncthreads();
  if (t < 64 && (j0+t) < IFACE_) {
    xi[b*XI_STRIDE + j0+t] = s_part[t]+s_part[64+t]+s_part[128+t]+s_part[192+t] + bias[j0+t];
  }
}

// ---------------- K2: per-batch (NOW 1024 THREADS): activations, wcw, usage, sort/alloc, ww ----------------
// Widened 256 -> 1024 threads: 1 element/thread in every 1024-wide phase.
// Same algorithm & barrier count; per-stage work /4, 16 waves to hide latency.
// s_red enlarged to 128 (16 waves x 8 slots); rkn phase guarded to waves 0-3.
__global__ __launch_bounds__(1024) void k_batch(
    const float* __restrict__ xi, const float* __restrict__ memory,
    const float* __restrict__ usage, const float* __restrict__ read_w,
    const float* __restrict__ write_w, const float* __restrict__ precedence,
    float* __restrict__ rkn, float* __restrict__ rs, float* __restrict__ er,
    float* __restrict__ wv, float* __restrict__ rm, float* __restrict__ ww_out,
    float* __restrict__ wwrw, float* __restrict__ prd, float* __restrict__ wrd) {
  int b = blockIdx.x; int t = threadIdx.x;
  int lane = t & 63; int wave = t >> 6;        // 16 waves
  __shared__ float s_act[472];
  __shared__ __align__(16) float s_key[64];
  __shared__ float s_wcw[1024];
  __shared__ unsigned long long s_k64[1024];
  __shared__ float s_ps[1024];
  __shared__ float s_alloc[1024];
  __shared__ float s_red[128];
  __shared__ float s_bc[2];

  for (int q = t; q < IFACE_; q += 1024) {
    float v = xi[b*XI_STRIDE+q];
    float a;
    if      (q < 256) a = tanhf(v);
    else if (q < 260) a = softp_(v);
    else if (q < 324) a = tanhf(v);
    else if (q < 325) a = softp_(v);
    else if (q < 389) a = sigm_(v);
    else if (q < 453) a = tanhf(v);
    else if (q < 459) a = sigm_(v);
    else              a = v;
    s_act[q] = a;
  }
  __syncthreads();
  if (t < 4) {
    float m0=s_act[459+3*t], m1=s_act[460+3*t], m2=s_act[461+3*t];
    float mx=fmaxf(m0,fmaxf(m1,m2));
    float e0=expf(m0-mx), e1=expf(m1-mx), e2=expf(m2-mx);
    float s=e0+e1+e2;
    rm[b*12+3*t+0]=e0/s; rm[b*12+3*t+1]=e1/s; rm[b*12+3*t+2]=e2/s;
  }
  if (t < 64) { er[b*64+t]=s_act[325+t]; wv[b*64+t]=s_act[389+t]; }
  if (wave < 4) {
    int r = wave;
    float v = s_act[r*64+lane];
    float ss = v*v;
    for (int off=32; off; off>>=1) ss += __shfl_xor(ss, off);
    rkn[((size_t)b*4+r)*64+lane] = v / (sqrtf(ss)+DELTA_);
    if (lane==0) rs[b*4+r] = s_act[256+r];
  }
  if (wave==4) {   // distinct wave from rkn work: a little more overlap
    float v = s_act[260+lane];
    float ss=v*v;
    for (int off=32; off; off>>=1) ss += __shfl_xor(ss, off);
    s_key[lane] = v/(sqrtf(ss)+DELTA_);
  }
  __syncthreads();
  float wstr = s_act[324], agv = s_act[457], wgv = s_act[458];

  for (int n=t; n<1024; n+=1024) {
    const float4* row = (const float4*)(memory + ((size_t)b*1024+n)*64);
    float dot=0.f, nn2=0.f;
    #pragma unroll
    for (int w4=0; w4<16; ++w4) {
      float4 m4 = row[w4];
      float4 k4 = ((const float4*)s_key)[w4];
      dot += dot4_(m4,k4);
      nn2 += dot4_(m4,m4);
    }
    s_wcw[n] = dot/(sqrtf(nn2)+DELTA_) * wstr;
  }
  __syncthreads();
  {
    float lm=-1e30f;
    for (int n=t;n<1024;n+=1024) lm=fmaxf(lm,s_wcw[n]);
    for (int off=32;off;off>>=1) lm=fmaxf(lm,__shfl_xor(lm,off));
    if (lane==0) s_red[wave]=lm;
    __syncthreads();
    if (t==0){
      float m=-1e30f;
      #pragma unroll
      for (int w=0;w<16;++w) m=fmaxf(m,s_red[w]);
      s_bc[0]=m;
    }
    __syncthreads();
    float mx=s_bc[0], ls=0.f;
    for (int n=t;n<1024;n+=1024){ float e=expf(s_wcw[n]-mx); s_wcw[n]=e; ls+=e; }
    for (int off=32;off;off>>=1) ls+=__shfl_xor(ls,off);
    if (lane==0) s_red[wave]=ls;
    __syncthreads();
    if (t==0){
      float s=0.f;
      #pragma unroll
      for (int w=0;w<16;++w) s+=s_red[w];
      s_bc[1]=s;
    }
    __syncthreads();
    float inv=1.f/s_bc[1];
    for (int n=t;n<1024;n+=1024) s_wcw[n]*=inv;
  }
  __syncthreads();

  for (int n=t; n<1024; n+=1024) {
    float us = usage[b*1024+n];
    float wwi = write_w[b*1024+n];
    float u = us + (1.f-us)*wwi;
    float psi = 1.f;
    #pragma unroll
    for (int r=0;r<4;++r) psi *= (1.f - s_act[453+r]*read_w[((size_t)b*4+r)*1024+n]);
    u *= psi;
    u = DELTA_ + (1.f-DELTA_)*u;
    unsigned int ub = __float_as_uint(u);
    s_k64[n] = ((unsigned long long)ub<<32) | (unsigned int)n;
  }

  for (int k=2; k<=1024; k<<=1) {
    for (int j=k>>1; j>0; j>>=1) {
      __syncthreads();
      for (int idx=t; idx<1024; idx+=1024) {
        int partner = idx ^ j;
        if (partner > idx) {
          unsigned long long a=s_k64[idx], c=s_k64[partner];
          bool asc = ((idx & k) == 0);
          bool sw = asc ? (a > c) : (a < c);
          if (sw) { s_k64[idx]=c; s_k64[partner]=a; }
        }
      }
    }
  }
  __syncthreads();

  for (int n=t;n<1024;n+=1024) s_ps[n] = __uint_as_float((unsigned int)(s_k64[n]>>32));
  __syncthreads();
  for (int off=1; off<1024; off<<=1) {
    float tmp = (t>=off) ? s_ps[t-off] : 1.f;
    __syncthreads();
    s_ps[t] *= tmp;
    __syncthreads();
  }
  for (int n=t;n<1024;n+=1024) {
    unsigned long long kv = s_k64[n];
    float su = __uint_as_float((unsigned int)(kv>>32));
    int oi = (int)(kv & 0xffffffffu);
    float prod = (n==0)?1.f:s_ps[n-1];
    s_alloc[oi] = (1.f-su)*prod;
  }
  __syncthreads();

  float pp[4]={0,0,0,0}, wp[4]={0,0,0,0};
  for (int n=t;n<1024;n+=1024) {
    float w_ = wgv*(agv*s_alloc[n] + (1.f-agv)*s_wcw[n]);
    ww_out[b*1024+n]=w_;
    float pn = precedence[b*1024+n];
    #pragma unroll
    for (int r=0;r<4;++r){
      float rwv = read_w[((size_t)b*4+r)*1024+n];
      wwrw[((size_t)b*4+r)*1024+n] = w_*rwv;
      pp[r] += pn*rwv;
      wp[r] += w_*rwv;
    }
  }
  #pragma unroll
  for (int r=0;r<4;++r){
    for (int off=32;off;off>>=1){ pp[r]+=__shfl_xor(pp[r],off); wp[r]+=__shfl_xor(wp[r],off); }
  }
  if (lane==0){
    #pragma unroll
    for (int r=0;r<4;++r){ s_red[wave*8+r]=pp[r]; s_red[wave*8+4+r]=wp[r]; }
  }
  __syncthreads();
  if (t<4){
    float s=0.f;
    #pragma unroll
    for (int w=0;w<16;++w) s+=s_red[w*8+t];
    prd[b*4+t]=s;
  } else if (t<8){
    int r=t-4; float s=0.f;
    #pragma unroll
    for (int w=0;w<16;++w) s+=s_red[w*8+4+r];
    wrd[b*4+r]=s;
  }
}

// ---------------- K3: new memory + row inverse norms ----------------
__global__ __launch_bounds__(256) void k_newmem(const float* __restrict__ memory,
    const float* __restrict__ ww, const float* __restrict__ er,
    const float* __restrict__ wv, float* __restrict__ newmem, float* __restrict__ invn) {
  int b = blockIdx.x;
  int n0 = blockIdx.y*64;
  int t = threadIdx.x;
  int lane16 = t & 15, rl = t >> 4;
  __shared__ float s_ww[64];
  __shared__ __align__(16) float s_er[64];
  __shared__ __align__(16) float s_wv[64];
  if (t < 64) s_ww[t] = ww[b*1024 + n0 + t];
  else if (t < 128) s_er[t-64] = er[b*64 + (t-64)];
  else if (t < 192) s_wv[t-128] = wv[b*64 + (t-128)];
  __syncthreads();
  float4 e4 = ((const float4*)s_er)[lane16];
  float4 v4 = ((const float4*)s_wv)[lane16];
  #pragma unroll
  for (int p=0;p<4;++p) {
    int rloc = p*16 + rl;
    int row = n0 + rloc;
    float wn = s_ww[rloc];
    size_t i4 = ((size_t)b*1024+row)*16 + lane16;
    float4 m4 = ((const float4*)memory)[i4];
    float4 nv;
    nv.x = m4.x*(1.f-wn*e4.x) + wn*v4.x;
    nv.y = m4.y*(1.f-wn*e4.y) + wn*v4.y;
    nv.z = m4.z*(1.f-wn*e4.z) + wn*v4.z;
    nv.w = m4.w*(1.f-wn*e4.w) + wn*v4.w;
    ((float4*)newmem)[i4] = nv;
    float ss = dot4_(nv,nv);
    ss += __shfl_xor(ss,1); ss += __shfl_xor(ss,2);
    ss += __shfl_xor(ss,4); ss += __shfl_xor(ss,8);
    if (lane16==0) invn[b*1024+row] = 1.f/(sqrtf(ss)+DELTA_);
  }
}

// ---------------- K4: shuffle-transpose scan + wave-uniform scalar weight loads ----------------
// (byte-for-byte round-4 restore: proven 76.4us, VGPR 52, no spill, WRITE 18.5MB)
__global__ __launch_bounds__(256) void k_scan(const float* __restrict__ L,
    const float* __restrict__ read_w, const float* __restrict__ wwrw,
    float* __restrict__ RAp, float* __restrict__ RBp,
    float* __restrict__ SAp, float* __restrict__ SBp,
    float* __restrict__ diag) {
  int b = blockIdx.x, rc = blockIdx.y, cc = blockIdx.z;
  int i0 = rc*64;
  int q = threadIdx.x;
  int r = q>>6, lc = q&63;
  int rr = (q>>4)&3, c4 = q&15;               // lane = 16*rr + c4
  __shared__ __align__(16) float RM[64*68];   // row-major tile, stride 68 (17 float4)
  __shared__ __align__(16) float CM[64*68];   // transposed tile CM[c][i]

  const float4* L4 = (const float4*)(L + (size_t)b*1048576);
  int ru = __builtin_amdgcn_readfirstlane(r); // wave-uniform reader id
  const float* wAbase = read_w + ((size_t)b*4+ru)*1024;
  const float* wBbase = wwrw   + ((size_t)b*4+ru)*1024;

  float4 pre[4];
  {
    int tc0 = cc*512;
    #pragma unroll
    for (int m=0;m<4;++m){
      int flat = q + 256*m;
      int row = flat>>4, cq = flat&15;
      pre[m] = L4[(size_t)(i0+row)*256 + (tc0>>2) + cq];
    }
  }
  float pa=0.f, pb=0.f;
  for (int t=0;t<8;++t) {
    int tc0 = cc*512 + t*64;
    __syncthreads();   // previous tile's LDS reads complete
    #pragma unroll
    for (int m=0;m<4;++m){
      int flat = q + 256*m;
      int row = flat>>4, cq = flat&15;
      ((float4*)RM)[row*17 + cq] = pre[m];    // bank-group (row+cq)%8: even spread
    }
    // CM fill via in-register 4x4 transpose (lanes rr=0..3 share c4, rows R0..R0+3)
    #pragma unroll
    for (int m=0;m<4;++m){
      float4 v = pre[m];
      // stage 1: xor 32 (partner rr^2): exchange 2x2 half-blocks
      float p0 = (rr<2) ? v.z : v.x;
      float p1 = (rr<2) ? v.w : v.y;
      float g0 = __shfl_xor(p0, 32);
      float g1 = __shfl_xor(p1, 32);
      float4 v1;
      if (rr<2) { v1.x=v.x; v1.y=v.y; v1.z=g0; v1.w=g1; }
      else      { v1.x=g0;  v1.y=g1;  v1.z=v.z; v1.w=v.w; }
      // stage 2: xor 16 (partner rr^1): interleave within 2x2 blocks
      float s0 = (rr&1) ? v1.x : v1.y;
      float s1 = (rr&1) ? v1.z : v1.w;
      float h0 = __shfl_xor(s0, 16);
      float h1 = __shfl_xor(s1, 16);
      float4 v2;
      if (rr&1) { v2.x=h0;  v2.y=v1.y; v2.z=h1;  v2.w=v1.w; }
      else      { v2.x=v1.x; v2.y=h0;  v2.z=v1.z; v2.w=h1;  }
      // v2 = column (4*c4+rr) of the 4x4 block, rows 16m+4r .. +3
      ((float4*)CM)[(4*c4+rr)*17 + 4*m + r] = v2;  // bank-group (4c4+rr+4m+r)%8: even
    }
    __syncthreads();   // tile visible
    if (t<7){
      int nc0 = tc0 + 64;
      #pragma unroll
      for (int m=0;m<4;++m){
        int flat = q + 256*m;
        int row = flat>>4, cq = flat&15;
        pre[m] = L4[(size_t)(i0+row)*256 + (nc0>>2) + cq];
      }
    }
    if (i0 == tc0 && q < 64) diag[b*1024 + i0 + q] = RM[q*68 + q];
    // phase A: row dots, accumulate across tiles (weights: wave-uniform scalar loads)
    {
      const float4* RM4 = (const float4*)RM;
      const float4* wA4 = (const float4*)(wAbase + tc0);
      const float4* wB4 = (const float4*)(wBbase + tc0);
      #pragma unroll
      for (int cq=0;cq<16;++cq){
        float4 a4 = RM4[lc*17 + cq];
        pa += dot4_(a4, wA4[cq]);
        pb += dot4_(a4, wB4[cq]);
      }
    }
    // phase B: col sums for this tile's 64 cols (row weights wave-uniform too)
    {
      const float4* CM4 = (const float4*)CM;
      const float4* wA4 = (const float4*)(wAbase + i0);
      const float4* wB4 = (const float4*)(wBbase + i0);
      float sa=0.f, sb=0.f;
      #pragma unroll
      for (int i4=0;i4<16;++i4){
        float4 c4v = CM4[lc*17 + i4];
        sa += dot4_(c4v, wA4[i4]);
        sb += dot4_(c4v, wB4[i4]);
      }
      SAp[(((size_t)(b*16+rc))*4+r)*1024 + tc0 + lc] = sa;
      SBp[(((size_t)(b*16+rc))*4+r)*1024 + tc0 + lc] = sb;
    }
  }
  RAp[(((size_t)(b*2+cc))*4+r)*1024 + i0 + lc] = pa;
  RBp[(((size_t)(b*2+cc))*4+r)*1024 + i0 + lc] = pb;
}

// ---------------- K5: content softmax + combine + readout (fused) ----------------
__global__ __launch_bounds__(256) void k_read(
    const float* __restrict__ newmem, const float* __restrict__ invn,
    const float* __restrict__ rkn, const float* __restrict__ rs,
    const float* __restrict__ rm, const float* __restrict__ RAp,
    const float* __restrict__ RBp, const float* __restrict__ SAp,
    const float* __restrict__ SBp, const float* __restrict__ ww,
    const float* __restrict__ precedence, const float* __restrict__ read_w,
    const float* __restrict__ diag, const float* __restrict__ prd,
    const float* __restrict__ wrd, float* __restrict__ out) {
  int b=blockIdx.x, r=blockIdx.y;
  int t=threadIdx.x, lane=t&63, wave=t>>6;
  int lane16 = t & 15, rl = t >> 4;
  __shared__ __align__(16) float s_key[64];
  __shared__ float s_arr[1024];
  __shared__ float s_red[4];
  __shared__ float s_bc[2];
  __shared__ __align__(16) float4 s_acc[16][16];
  if (t<64) s_key[t]=rkn[((size_t)b*4+r)*64+t];
  __syncthreads();
  float rstr = rs[b*4+r];
  float4 key4 = ((const float4*)s_key)[lane16];
  for (int p=0;p<64;++p) {
    int row = p*16 + rl;
    float4 m4 = ((const float4*)newmem)[((size_t)b*1024+row)*16 + lane16];
    float d = dot4_(m4, key4);
    d += __shfl_xor(d,1); d += __shfl_xor(d,2);
    d += __shfl_xor(d,4); d += __shfl_xor(d,8);
    if (lane16==0) s_arr[row] = d * invn[b*1024+row] * rstr;
  }
  __syncthreads();
  {
    float lm=-1e30f;
    for (int n=t;n<1024;n+=256) lm=fmaxf(lm,s_arr[n]);
    for (int off=32;off;off>>=1) lm=fmaxf(lm,__shfl_xor(lm,off));
    if (lane==0) s_red[wave]=lm;
    __syncthreads();
    if (t==0) s_bc[0]=fmaxf(fmaxf(s_red[0],s_red[1]),fmaxf(s_red[2],s_red[3]));
    __syncthreads();
    float mx=s_bc[0], ls=0.f;
    for (int n=t;n<1024;n+=256){ float e=expf(s_arr[n]-mx); s_arr[n]=e; ls+=e; }
    for (int off=32;off;off>>=1) ls+=__shfl_xor(ls,off);
    if (lane==0) s_red[wave]=ls;
    __syncthreads();
    if (t==0) s_bc[1]=s_red[0]+s_red[1]+s_red[2]+s_red[3];
    __syncthreads();
    float inv=1.f/s_bc[1];
    for (int n=t;n<1024;n+=256) s_arr[n]*=inv;
  }
  __syncthreads();
  float m0=rm[b*12+r*3+0], m1=rm[b*12+r*3+1], m2=rm[b*12+r*3+2];
  float pd=prd[b*4+r], wd=wrd[b*4+r];
  // thread-local per-n combine: no cross-thread hazard, no barriers needed
  for (int n=t;n<1024;n+=256) {
    float ra=0.f, rb=0.f;
    #pragma unroll
    for (int cc=0;cc<2;++cc){
      ra += RAp[(((size_t)(b*2+cc))*4+r)*1024+n];
      rb += RBp[(((size_t)(b*2+cc))*4+r)*1024+n];
    }
    float sa=0.f, sb=0.f;
    #pragma unroll
    for (int rc=0;rc<16;++rc){
      sa+=SAp[(((size_t)(b*16+rc))*4+r)*1024+n];
      sb+=SBp[(((size_t)(b*16+rc))*4+r)*1024+n];
    }
    float w_ = ww[b*1024+n];
    float pn = precedence[b*1024+n];
    float rwv= read_w[((size_t)b*4+r)*1024+n];
    float dg = diag[b*1024+n];
    float fwd = (1.f-w_)*ra - rb + w_*pd - ((1.f-2.f*w_)*dg + w_*pn)*rwv;
    float bwd = (1.f-w_)*sa - sb + pn*(wd - w_*rwv) - (1.f-2.f*w_)*dg*rwv;
    float crw = s_arr[n];
    s_arr[n] = m0*bwd + m1*crw + m2*fwd;
  }
  __syncthreads();
  float4 acc = {0,0,0,0};
  for (int p=0;p<64;++p) {
    int row = p*16 + rl;
    float4 m4 = ((const float4*)newmem)[((size_t)b*1024+row)*16 + lane16];
    float s = s_arr[row];
    acc.x += s*m4.x; acc.y += s*m4.y; acc.z += s*m4.z; acc.w += s*m4.w;
  }
  s_acc[rl][lane16] = acc;
  __syncthreads();
  if (t < 16) {
    float4 tot = {0,0,0,0};
    #pragma unroll
    for (int g=0; g<16; ++g) {
      float4 v = s_acc[g][t];
      tot.x+=v.x; tot.y+=v.y; tot.z+=v.z; tot.w+=v.w;
    }
    ((float4*)(out + (b*4+r)*64))[t] = tot;
  }
}

extern "C" void kernel_launch(void* const* d_in, const int* in_sizes, int n_in,
                              void* d_out, int out_size, void* d_ws, size_t ws_size,
                              hipStream_t stream) {
  const float* x      = (const float*)d_in[0];
  const float* W_if   = (const float*)d_in[1];
  const float* b_if   = (const float*)d_in[2];
  const float* memory = (const float*)d_in[3];
  const float* link   = (const float*)d_in[4];
  const float* prec   = (const float*)d_in[5];
  const float* read_w = (const float*)d_in[6];
  const float* write_w= (const float*)d_in[7];
  const float* usage  = (const float*)d_in[8];
  float* out = (float*)d_out;
  float* ws = (float*)d_ws;

  float* xi   = ws + OFF_XI;
  float* rkn  = ws + OFF_RKN;
  float* rs   = ws + OFF_RS;
  float* er   = ws + OFF_ER;
  float* wv   = ws + OFF_WV;
  float* rm   = ws + OFF_RM;
  float* wwp  = ws + OFF_WW;
  float* wwrw = ws + OFF_WWRW;
  float* prd  = ws + OFF_PRD;
  float* wrd  = ws + OFF_WRD;
  float* invn = ws + OFF_INVN;
  float* diag = ws + OFF_DIAG;
  float* nm   = ws + OFF_NM;
  float* RAp  = ws + OFF_RAP;
  float* RBp  = ws + OFF_RBP;
  float* SAp  = ws + OFF_SAP;
  float* SBp  = ws + OFF_SBP;

  k_xi<<<dim3(32,8), 256, 0, stream>>>(x, W_if, b_if, xi);
  k_batch<<<dim3(32), 1024, 0, stream>>>(xi, memory, usage, read_w, write_w, prec,
                                         rkn, rs, er, wv, rm, wwp, wwrw, prd, wrd);
  k_scan<<<dim3(32,16,2), 256, 0, stream>>>(link, read_w, wwrw, RAp, RBp, SAp, SBp, diag);
  k_newmem<<<dim3(32,16), 256, 0, stream>>>(memory, wwp, er, wv, nm, invn);
  k_read<<<dim3(32,4), 256, 0, stream>>>(nm, invn, rkn, rs, rm, RAp, RBp, SAp, SBp,
                                         wwp, prec, read_w, diag, prd, wrd, out);
}

// Round 7
// 315.599 us; speedup vs baseline: 1.3335x; 1.0763x over previous
//
#include <hip/hip_runtime.h>
#include <math.h>

#define DELTA_ 1e-6f
#define IFACE_ 471
#define XI_STRIDE 480

// workspace offsets (in floats)
#define OFF_XI    0            // 32*480
#define OFF_RKN   15360        // 32*4*64
#define OFF_RS    23552        // 32*4
#define OFF_ER    23680        // 32*64
#define OFF_WV    25728        // 32*64
#define OFF_RM    27776        // 32*12
#define OFF_WW    28160        // 32*1024
#define OFF_WWRW  60928        // 32*4*1024
#define OFF_PRD   192000       // 32*4
#define OFF_WRD   192128       // 32*4
#define OFF_INVN  192256       // 32*1024
#define OFF_DIAG  225024       // 32*1024
#define OFF_NM    257792       // 32*1024*64
#define OFF_RAP   2354944      // 32*2cc*4r*1024
#define OFF_RBP   2617088      // 32*2cc*4r*1024
#define OFF_SAP   2879232      // 32*16rc*4r*1024
#define OFF_SBP   4976384      // 32*16rc*4r*1024
// total 7073536 floats = 27 MB

__device__ __forceinline__ float sigm_(float x){ return 1.f/(1.f+expf(-x)); }
__device__ __forceinline__ float softp_(float x){ return fmaxf(x,0.f)+log1pf(expf(-fabsf(x))); }
__device__ __forceinline__ float dot4_(float4 a, float4 b){ return a.x*b.x+a.y*b.y+a.z*b.z+a.w*b.w; }

// ---------------- K1: xi = x @ W_if + b_if ----------------
__global__ __launch_bounds__(256) void k_xi(const float* __restrict__ x,
    const float* __restrict__ W, const float* __restrict__ bias,
    float* __restrict__ xi) {
  int b = blockIdx.x;
  int j0 = blockIdx.y*64;
  int t = threadIdx.x;
  int jl = t & 63, kq = t >> 6;
  __shared__ __align__(16) float sx[1024];
  __shared__ float s_part[256];
  for (int q=t; q<256; q+=256) ((float4*)sx)[q] = ((const float4*)(x + b*1024))[q];
  __syncthreads();
  int j = j0 + jl;
  int jc = j < IFACE_ ? j : IFACE_-1;
  float acc = 0.f;
  const float* Wp = W + (size_t)kq*256*IFACE_ + jc;
  #pragma unroll 4
  for (int k=0;k<256;++k) acc += sx[kq*256+k]*Wp[(size_t)k*IFACE_];
  s_part[t] = acc;
  __syncthreads();
  if (t < 64 && (j0+t) < IFACE_) {
    xi[b*XI_STRIDE + j0+t] = s_part[t]+s_part[64+t]+s_part[128+t]+s_part[192+t] + bias[j0+t];
  }
}

// ---------------- K2: per-batch (1024 THREADS): activations, wcw, usage, sort/alloc, ww ----------------
__global__ __launch_bounds__(1024) void k_batch(
    const float* __restrict__ xi, const float* __restrict__ memory,
    const float* __restrict__ usage, const float* __restrict__ read_w,
    const float* __restrict__ write_w, const float* __restrict__ precedence,
    float* __restrict__ rkn, float* __restrict__ rs, float* __restrict__ er,
    float* __restrict__ wv, float* __restrict__ rm, float* __restrict__ ww_out,
    float* __restrict__ wwrw, float* __restrict__ prd, float* __restrict__ wrd) {
  int b = blockIdx.x; int t = threadIdx.x;
  int lane = t & 63; int wave = t >> 6;        // 16 waves
  __shared__ float s_act[472];
  __shared__ __align__(16) float s_key[64];
  __shared__ float s_wcw[1024];
  __shared__ unsigned long long s_k64[1024];
  __shared__ float s_ps[1024];
  __shared__ float s_alloc[1024];
  __shared__ float s_red[128];
  __shared__ float s_bc[2];

  for (int q = t; q < IFACE_; q += 1024) {
    float v = xi[b*XI_STRIDE+q];
    float a;
    if      (q < 256) a = tanhf(v);
    else if (q < 260) a = softp_(v);
    else if (q < 324) a = tanhf(v);
    else if (q < 325) a = softp_(v);
    else if (q < 389) a = sigm_(v);
    else if (q < 453) a = tanhf(v);
    else if (q < 459) a = sigm_(v);
    else              a = v;
    s_act[q] = a;
  }
  __syncthreads();
  if (t < 4) {
    float m0=s_act[459+3*t], m1=s_act[460+3*t], m2=s_act[461+3*t];
    float mx=fmaxf(m0,fmaxf(m1,m2));
    float e0=expf(m0-mx), e1=expf(m1-mx), e2=expf(m2-mx);
    float s=e0+e1+e2;
    rm[b*12+3*t+0]=e0/s; rm[b*12+3*t+1]=e1/s; rm[b*12+3*t+2]=e2/s;
  }
  if (t < 64) { er[b*64+t]=s_act[325+t]; wv[b*64+t]=s_act[389+t]; }
  if (wave < 4) {
    int r = wave;
    float v = s_act[r*64+lane];
    float ss = v*v;
    for (int off=32; off; off>>=1) ss += __shfl_xor(ss, off);
    rkn[((size_t)b*4+r)*64+lane] = v / (sqrtf(ss)+DELTA_);
    if (lane==0) rs[b*4+r] = s_act[256+r];
  }
  if (wave==4) {
    float v = s_act[260+lane];
    float ss=v*v;
    for (int off=32; off; off>>=1) ss += __shfl_xor(ss, off);
    s_key[lane] = v/(sqrtf(ss)+DELTA_);
  }
  __syncthreads();
  float wstr = s_act[324], agv = s_act[457], wgv = s_act[458];

  for (int n=t; n<1024; n+=1024) {
    const float4* row = (const float4*)(memory + ((size_t)b*1024+n)*64);
    float dot=0.f, nn2=0.f;
    #pragma unroll
    for (int w4=0; w4<16; ++w4) {
      float4 m4 = row[w4];
      float4 k4 = ((const float4*)s_key)[w4];
      dot += dot4_(m4,k4);
      nn2 += dot4_(m4,m4);
    }
    s_wcw[n] = dot/(sqrtf(nn2)+DELTA_) * wstr;
  }
  __syncthreads();
  {
    float lm=-1e30f;
    for (int n=t;n<1024;n+=1024) lm=fmaxf(lm,s_wcw[n]);
    for (int off=32;off;off>>=1) lm=fmaxf(lm,__shfl_xor(lm,off));
    if (lane==0) s_red[wave]=lm;
    __syncthreads();
    if (t==0){
      float m=-1e30f;
      #pragma unroll
      for (int w=0;w<16;++w) m=fmaxf(m,s_red[w]);
      s_bc[0]=m;
    }
    __syncthreads();
    float mx=s_bc[0], ls=0.f;
    for (int n=t;n<1024;n+=1024){ float e=expf(s_wcw[n]-mx); s_wcw[n]=e; ls+=e; }
    for (int off=32;off;off>>=1) ls+=__shfl_xor(ls,off);
    if (lane==0) s_red[wave]=ls;
    __syncthreads();
    if (t==0){
      float s=0.f;
      #pragma unroll
      for (int w=0;w<16;++w) s+=s_red[w];
      s_bc[1]=s;
    }
    __syncthreads();
    float inv=1.f/s_bc[1];
    for (int n=t;n<1024;n+=1024) s_wcw[n]*=inv;
  }
  __syncthreads();

  for (int n=t; n<1024; n+=1024) {
    float us = usage[b*1024+n];
    float wwi = write_w[b*1024+n];
    float u = us + (1.f-us)*wwi;
    float psi = 1.f;
    #pragma unroll
    for (int r=0;r<4;++r) psi *= (1.f - s_act[453+r]*read_w[((size_t)b*4+r)*1024+n]);
    u *= psi;
    u = DELTA_ + (1.f-DELTA_)*u;
    unsigned int ub = __float_as_uint(u);
    s_k64[n] = ((unsigned long long)ub<<32) | (unsigned int)n;
  }

  for (int k=2; k<=1024; k<<=1) {
    for (int j=k>>1; j>0; j>>=1) {
      __syncthreads();
      for (int idx=t; idx<1024; idx+=1024) {
        int partner = idx ^ j;
        if (partner > idx) {
          unsigned long long a=s_k64[idx], c=s_k64[partner];
          bool asc = ((idx & k) == 0);
          bool sw = asc ? (a > c) : (a < c);
          if (sw) { s_k64[idx]=c; s_k64[partner]=a; }
        }
      }
    }
  }
  __syncthreads();

  for (int n=t;n<1024;n+=1024) s_ps[n] = __uint_as_float((unsigned int)(s_k64[n]>>32));
  __syncthreads();
  for (int off=1; off<1024; off<<=1) {
    float tmp = (t>=off) ? s_ps[t-off] : 1.f;
    __syncthreads();
    s_ps[t] *= tmp;
    __syncthreads();
  }
  for (int n=t;n<1024;n+=1024) {
    unsigned long long kv = s_k64[n];
    float su = __uint_as_float((unsigned int)(kv>>32));
    int oi = (int)(kv & 0xffffffffu);
    float prod = (n==0)?1.f:s_ps[n-1];
    s_alloc[oi] = (1.f-su)*prod;
  }
  __syncthreads();

  float pp[4]={0,0,0,0}, wp[4]={0,0,0,0};
  for (int n=t;n<1024;n+=1024) {
    float w_ = wgv*(agv*s_alloc[n] + (1.f-agv)*s_wcw[n]);
    ww_out[b*1024+n]=w_;
    float pn = precedence[b*1024+n];
    #pragma unroll
    for (int r=0;r<4;++r){
      float rwv = read_w[((size_t)b*4+r)*1024+n];
      wwrw[((size_t)b*4+r)*1024+n] = w_*rwv;
      pp[r] += pn*rwv;
      wp[r] += w_*rwv;
    }
  }
  #pragma unroll
  for (int r=0;r<4;++r){
    for (int off=32;off;off>>=1){ pp[r]+=__shfl_xor(pp[r],off); wp[r]+=__shfl_xor(wp[r],off); }
  }
  if (lane==0){
    #pragma unroll
    for (int r=0;r<4;++r){ s_red[wave*8+r]=pp[r]; s_red[wave*8+4+r]=wp[r]; }
  }
  __syncthreads();
  if (t<4){
    float s=0.f;
    #pragma unroll
    for (int w=0;w<16;++w) s+=s_red[w*8+t];
    prd[b*4+t]=s;
  } else if (t<8){
    int r=t-4; float s=0.f;
    #pragma unroll
    for (int w=0;w<16;++w) s+=s_red[w*8+4+r];
    wrd[b*4+r]=s;
  }
}

// ---------------- K3: new memory + row inverse norms ----------------
__global__ __launch_bounds__(256) void k_newmem(const float* __restrict__ memory,
    const float* __restrict__ ww, const float* __restrict__ er,
    const float* __restrict__ wv, float* __restrict__ newmem, float* __restrict__ invn) {
  int b = blockIdx.x;
  int n0 = blockIdx.y*64;
  int t = threadIdx.x;
  int lane16 = t & 15, rl = t >> 4;
  __shared__ float s_ww[64];
  __shared__ __align__(16) float s_er[64];
  __shared__ __align__(16) float s_wv[64];
  if (t < 64) s_ww[t] = ww[b*1024 + n0 + t];
  else if (t < 128) s_er[t-64] = er[b*64 + (t-64)];
  else if (t < 192) s_wv[t-128] = wv[b*64 + (t-128)];
  __syncthreads();
  float4 e4 = ((const float4*)s_er)[lane16];
  float4 v4 = ((const float4*)s_wv)[lane16];
  #pragma unroll
  for (int p=0;p<4;++p) {
    int rloc = p*16 + rl;
    int row = n0 + rloc;
    float wn = s_ww[rloc];
    size_t i4 = ((size_t)b*1024+row)*16 + lane16;
    float4 m4 = ((const float4*)memory)[i4];
    float4 nv;
    nv.x = m4.x*(1.f-wn*e4.x) + wn*v4.x;
    nv.y = m4.y*(1.f-wn*e4.y) + wn*v4.y;
    nv.z = m4.z*(1.f-wn*e4.z) + wn*v4.z;
    nv.w = m4.w*(1.f-wn*e4.w) + wn*v4.w;
    ((float4*)newmem)[i4] = nv;
    float ss = dot4_(nv,nv);
    ss += __shfl_xor(ss,1); ss += __shfl_xor(ss,2);
    ss += __shfl_xor(ss,4); ss += __shfl_xor(ss,8);
    if (lane16==0) invn[b*1024+row] = 1.f/(sqrtf(ss)+DELTA_);
  }
}

// ---------------- K4: shuffle-transpose scan + wave-uniform scalar weight loads ----------------
// (byte-for-byte round-4 restore: proven 76.4us, VGPR 52, no spill, WRITE 18.5MB)
__global__ __launch_bounds__(256) void k_scan(const float* __restrict__ L,
    const float* __restrict__ read_w, const float* __restrict__ wwrw,
    float* __restrict__ RAp, float* __restrict__ RBp,
    float* __restrict__ SAp, float* __restrict__ SBp,
    float* __restrict__ diag) {
  int b = blockIdx.x, rc = blockIdx.y, cc = blockIdx.z;
  int i0 = rc*64;
  int q = threadIdx.x;
  int r = q>>6, lc = q&63;
  int rr = (q>>4)&3, c4 = q&15;               // lane = 16*rr + c4
  __shared__ __align__(16) float RM[64*68];   // row-major tile, stride 68 (17 float4)
  __shared__ __align__(16) float CM[64*68];   // transposed tile CM[c][i]

  const float4* L4 = (const float4*)(L + (size_t)b*1048576);
  int ru = __builtin_amdgcn_readfirstlane(r); // wave-uniform reader id
  const float* wAbase = read_w + ((size_t)b*4+ru)*1024;
  const float* wBbase = wwrw   + ((size_t)b*4+ru)*1024;

  float4 pre[4];
  {
    int tc0 = cc*512;
    #pragma unroll
    for (int m=0;m<4;++m){
      int flat = q + 256*m;
      int row = flat>>4, cq = flat&15;
      pre[m] = L4[(size_t)(i0+row)*256 + (tc0>>2) + cq];
    }
  }
  float pa=0.f, pb=0.f;
  for (int t=0;t<8;++t) {
    int tc0 = cc*512 + t*64;
    __syncthreads();   // previous tile's LDS reads complete
    #pragma unroll
    for (int m=0;m<4;++m){
      int flat = q + 256*m;
      int row = flat>>4, cq = flat&15;
      ((float4*)RM)[row*17 + cq] = pre[m];    // bank-group (row+cq)%8: even spread
    }
    // CM fill via in-register 4x4 transpose (lanes rr=0..3 share c4, rows R0..R0+3)
    #pragma unroll
    for (int m=0;m<4;++m){
      float4 v = pre[m];
      // stage 1: xor 32 (partner rr^2): exchange 2x2 half-blocks
      float p0 = (rr<2) ? v.z : v.x;
      float p1 = (rr<2) ? v.w : v.y;
      float g0 = __shfl_xor(p0, 32);
      float g1 = __shfl_xor(p1, 32);
      float4 v1;
      if (rr<2) { v1.x=v.x; v1.y=v.y; v1.z=g0; v1.w=g1; }
      else      { v1.x=g0;  v1.y=g1;  v1.z=v.z; v1.w=v.w; }
      // stage 2: xor 16 (partner rr^1): interleave within 2x2 blocks
      float s0 = (rr&1) ? v1.x : v1.y;
      float s1 = (rr&1) ? v1.z : v1.w;
      float h0 = __shfl_xor(s0, 16);
      float h1 = __shfl_xor(s1, 16);
      float4 v2;
      if (rr&1) { v2.x=h0;  v2.y=v1.y; v2.z=h1;  v2.w=v1.w; }
      else      { v2.x=v1.x; v2.y=h0;  v2.z=v1.z; v2.w=h1;  }
      // v2 = column (4*c4+rr) of the 4x4 block, rows 16m+4r .. +3
      ((float4*)CM)[(4*c4+rr)*17 + 4*m + r] = v2;  // bank-group (4c4+rr+4m+r)%8: even
    }
    __syncthreads();   // tile visible
    if (t<7){
      int nc0 = tc0 + 64;
      #pragma unroll
      for (int m=0;m<4;++m){
        int flat = q + 256*m;
        int row = flat>>4, cq = flat&15;
        pre[m] = L4[(size_t)(i0+row)*256 + (nc0>>2) + cq];
      }
    }
    if (i0 == tc0 && q < 64) diag[b*1024 + i0 + q] = RM[q*68 + q];
    // phase A: row dots, accumulate across tiles (weights: wave-uniform scalar loads)
    {
      const float4* RM4 = (const float4*)RM;
      const float4* wA4 = (const float4*)(wAbase + tc0);
      const float4* wB4 = (const float4*)(wBbase + tc0);
      #pragma unroll
      for (int cq=0;cq<16;++cq){
        float4 a4 = RM4[lc*17 + cq];
        pa += dot4_(a4, wA4[cq]);
        pb += dot4_(a4, wB4[cq]);
      }
    }
    // phase B: col sums for this tile's 64 cols (row weights wave-uniform too)
    {
      const float4* CM4 = (const float4*)CM;
      const float4* wA4 = (const float4*)(wAbase + i0);
      const float4* wB4 = (const float4*)(wBbase + i0);
      float sa=0.f, sb=0.f;
      #pragma unroll
      for (int i4=0;i4<16;++i4){
        float4 c4v = CM4[lc*17 + i4];
        sa += dot4_(c4v, wA4[i4]);
        sb += dot4_(c4v, wB4[i4]);
      }
      SAp[(((size_t)(b*16+rc))*4+r)*1024 + tc0 + lc] = sa;
      SBp[(((size_t)(b*16+rc))*4+r)*1024 + tc0 + lc] = sb;
    }
  }
  RAp[(((size_t)(b*2+cc))*4+r)*1024 + i0 + lc] = pa;
  RBp[(((size_t)(b*2+cc))*4+r)*1024 + i0 + lc] = pb;
}

// ---------------- K5: content softmax + combine + readout (NOW 1024 THREADS) ----------------
// Widened 256 -> 1024: row loops 64 -> 16 iterations, softmax/combine 1 elem/thread,
// 16 waves/block to hide the global-load + shuffle latency chains that dominated at
// 4 waves. s_acc grown to [64][16] (16 KB), s_red to 16 waves. Same math, same
// summation structure per element; grid unchanged (32,4).
__global__ __launch_bounds__(1024) void k_read(
    const float* __restrict__ newmem, const float* __restrict__ invn,
    const float* __restrict__ rkn, const float* __restrict__ rs,
    const float* __restrict__ rm, const float* __restrict__ RAp,
    const float* __restrict__ RBp, const float* __restrict__ SAp,
    const float* __restrict__ SBp, const float* __restrict__ ww,
    const float* __restrict__ precedence, const float* __restrict__ read_w,
    const float* __restrict__ diag, const float* __restrict__ prd,
    const float* __restrict__ wrd, float* __restrict__ out) {
  int b=blockIdx.x, r=blockIdx.y;
  int t=threadIdx.x, lane=t&63, wave=t>>6;   // 16 waves
  int lane16 = t & 15, rl = t >> 4;          // rl in 0..63
  __shared__ __align__(16) float s_key[64];
  __shared__ float s_arr[1024];
  __shared__ float s_red[16];
  __shared__ float s_bc[2];
  __shared__ __align__(16) float4 s_acc[64][16];   // 16 KB
  if (t<64) s_key[t]=rkn[((size_t)b*4+r)*64+t];
  __syncthreads();
  float rstr = rs[b*4+r];
  float4 key4 = ((const float4*)s_key)[lane16];
  for (int p=0;p<16;++p) {
    int row = p*64 + rl;
    float4 m4 = ((const float4*)newmem)[((size_t)b*1024+row)*16 + lane16];
    float d = dot4_(m4, key4);
    d += __shfl_xor(d,1); d += __shfl_xor(d,2);
    d += __shfl_xor(d,4); d += __shfl_xor(d,8);
    if (lane16==0) s_arr[row] = d * invn[b*1024+row] * rstr;
  }
  __syncthreads();
  {
    float lm = s_arr[t];
    for (int off=32;off;off>>=1) lm=fmaxf(lm,__shfl_xor(lm,off));
    if (lane==0) s_red[wave]=lm;
    __syncthreads();
    if (t==0){
      float m=-1e30f;
      #pragma unroll
      for (int w=0;w<16;++w) m=fmaxf(m,s_red[w]);
      s_bc[0]=m;
    }
    __syncthreads();
    float mx=s_bc[0];
    float e=expf(s_arr[t]-mx); s_arr[t]=e; float ls=e;
    for (int off=32;off;off>>=1) ls+=__shfl_xor(ls,off);
    if (lane==0) s_red[wave]=ls;
    __syncthreads();
    if (t==0){
      float s=0.f;
      #pragma unroll
      for (int w=0;w<16;++w) s+=s_red[w];
      s_bc[1]=s;
    }
    __syncthreads();
    float inv=1.f/s_bc[1];
    s_arr[t]*=inv;
  }
  __syncthreads();
  float m0=rm[b*12+r*3+0], m1=rm[b*12+r*3+1], m2=rm[b*12+r*3+2];
  float pd=prd[b*4+r], wd=wrd[b*4+r];
  // thread-local combine: n = t (1 elem/thread), no cross-thread hazard
  {
    int n = t;
    float ra=0.f, rb=0.f;
    #pragma unroll
    for (int cc=0;cc<2;++cc){
      ra += RAp[(((size_t)(b*2+cc))*4+r)*1024+n];
      rb += RBp[(((size_t)(b*2+cc))*4+r)*1024+n];
    }
    float sa=0.f, sb=0.f;
    #pragma unroll
    for (int rc=0;rc<16;++rc){
      sa+=SAp[(((size_t)(b*16+rc))*4+r)*1024+n];
      sb+=SBp[(((size_t)(b*16+rc))*4+r)*1024+n];
    }
    float w_ = ww[b*1024+n];
    float pn = precedence[b*1024+n];
    float rwv= read_w[((size_t)b*4+r)*1024+n];
    float dg = diag[b*1024+n];
    float fwd = (1.f-w_)*ra - rb + w_*pd - ((1.f-2.f*w_)*dg + w_*pn)*rwv;
    float bwd = (1.f-w_)*sa - sb + pn*(wd - w_*rwv) - (1.f-2.f*w_)*dg*rwv;
    float crw = s_arr[n];
    s_arr[n] = m0*bwd + m1*crw + m2*fwd;
  }
  __syncthreads();
  float4 acc = {0,0,0,0};
  for (int p=0;p<16;++p) {
    int row = p*64 + rl;
    float4 m4 = ((const float4*)newmem)[((size_t)b*1024+row)*16 + lane16];
    float s = s_arr[row];
    acc.x += s*m4.x; acc.y += s*m4.y; acc.z += s*m4.z; acc.w += s*m4.w;
  }
  s_acc[rl][lane16] = acc;
  __syncthreads();
  if (t < 16) {
    float4 tot = {0,0,0,0};
    #pragma unroll
    for (int g=0; g<64; ++g) {
      float4 v = s_acc[g][t];
      tot.x+=v.x; tot.y+=v.y; tot.z+=v.z; tot.w+=v.w;
    }
    ((float4*)(out + (b*4+r)*64))[t] = tot;
  }
}

extern "C" void kernel_launch(void* const* d_in, const int* in_sizes, int n_in,
                              void* d_out, int out_size, void* d_ws, size_t ws_size,
                              hipStream_t stream) {
  const float* x      = (const float*)d_in[0];
  const float* W_if   = (const float*)d_in[1];
  const float* b_if   = (const float*)d_in[2];
  const float* memory = (const float*)d_in[3];
  const float* link   = (const float*)d_in[4];
  const float* prec   = (const float*)d_in[5];
  const float* read_w = (const float*)d_in[6];
  const float* write_w= (const float*)d_in[7];
  const float* usage  = (const float*)d_in[8];
  float* out = (float*)d_out;
  float* ws = (float*)d_ws;

  float* xi   = ws + OFF_XI;
  float* rkn  = ws + OFF_RKN;
  float* rs   = ws + OFF_RS;
  float* er   = ws + OFF_ER;
  float* wv   = ws + OFF_WV;
  float* rm   = ws + OFF_RM;
  float* wwp  = ws + OFF_WW;
  float* wwrw = ws + OFF_WWRW;
  float* prd  = ws + OFF_PRD;
  float* wrd  = ws + OFF_WRD;
  float* invn = ws + OFF_INVN;
  float* diag = ws + OFF_DIAG;
  float* nm   = ws + OFF_NM;
  float* RAp  = ws + OFF_RAP;
  float* RBp  = ws + OFF_RBP;
  float* SAp  = ws + OFF_SAP;
  float* SBp  = ws + OFF_SBP;

  k_xi<<<dim3(32,8), 256, 0, stream>>>(x, W_if, b_if, xi);
  k_batch<<<dim3(32), 1024, 0, stream>>>(xi, memory, usage, read_w, write_w, prec,
                                         rkn, rs, er, wv, rm, wwp, wwrw, prd, wrd);
  k_scan<<<dim3(32,16,2), 256, 0, stream>>>(link, read_w, wwrw, RAp, RBp, SAp, SBp, diag);
  k_newmem<<<dim3(32,16), 256, 0, stream>>>(memory, wwp, er, wv, nm, invn);
  k_read<<<dim3(32,4), 1024, 0, stream>>>(nm, invn, rkn, rs, rm, RAp, RBp, SAp, SBp,
                                          wwp, prec, read_w, diag, prd, wrd, out);
}